// Round 1
// baseline (1606.712 us; speedup 1.0000x reference)
//
#include <hip/hip_runtime.h>

#define NW   8192
#define NT   49
#define CDIM 192
#define NH   6
#define HD   32

typedef __attribute__((ext_vector_type(4))) float f32x4;
typedef __attribute__((ext_vector_type(8))) short bf16x8;

__device__ __forceinline__ unsigned short f2b(float f) {
  union { float f; unsigned u; } v; v.f = f;
  unsigned r = v.u + 0x7fffu + ((v.u >> 16) & 1u);   // round-to-nearest-even
  return (unsigned short)(r >> 16);
}
__device__ __forceinline__ float b2f(unsigned short u) {
  union { unsigned u; float f; } v; v.u = ((unsigned)u) << 16; return v.f;
}

// LDS plan (59.7 KB). Order matters: MFMA fragment reads of padded rows (m up to 63)
// overflow past 49-row buffers into the NEXT buffer -- always in-bounds, and finite
// because we zero the whole struct at block start.
struct __align__(16) Smem {
  unsigned short xb[NT][200];   // x (bf16), row stride 200 (400B, 16B-mult, bank-safe)
  unsigned short Ob[NT][200];   // attention output (bf16)
  unsigned short qh[NT][40];    // per-head q [i][d], stride 40 (80B)
  unsigned short kh[NT][40];    // per-head k [i][d]
  unsigned short vT[HD][72];    // per-head v transposed [d][j], stride 72 (144B)
  unsigned short P [64][72];    // per-head exp(S-m) (bf16), 64 rows (padded i)
  float sinv[64];               // per-row 1/sum
};

// ---- prep: weight transpose+cvt (scale folded into q cols), bias gather ----
__global__ void prep_w(const float* __restrict__ qkv_w, const float* __restrict__ qkv_b,
                       const float* __restrict__ proj_w,
                       unsigned short* __restrict__ wT, unsigned short* __restrict__ projT,
                       float* __restrict__ qb) {
  int idx = blockIdx.x * 256 + threadIdx.x;
  const float scale = 0.17677669529663687f;  // 32^-0.5
  if (idx < 576 * 192) {                     // wT[n][c] = qkv_w[c][n] (*scale for q cols)
    int n = idx / 192, c = idx % 192;
    float v = qkv_w[c * 576 + n];
    if (n < 192) v *= scale;
    wT[idx] = f2b(v);
  } else if (idx < 576 * 192 + 192 * 192) {  // projT[n][c] = proj_w[c][n]
    int j = idx - 576 * 192;
    int n = j / 192, c = j % 192;
    projT[j] = f2b(proj_w[c * 192 + n]);
  } else if (idx < 576 * 192 + 192 * 192 + 576) {
    int n = idx - (576 * 192 + 192 * 192);
    float v = qkv_b[n];
    if (n < 192) v *= scale;
    qb[n] = v;
  }
}

// biasF[h][it][jt][lane][reg] bf16, C-fragment order; -1e30 outside 49x49 = fused mask
__global__ void prep_bias(const float* __restrict__ table, const int* __restrict__ rel,
                          unsigned short* __restrict__ biasF) {
  int idx = blockIdx.x * 256 + threadIdx.x;
  if (idx >= NH * 4 * 4 * 64 * 4) return;
  int reg = idx & 3, lane = (idx >> 2) & 63, jt = (idx >> 8) & 3,
      it = (idx >> 10) & 3, h = idx >> 12;
  int i = it * 16 + (lane >> 4) * 4 + reg;
  int j = jt * 16 + (lane & 15);
  float v = -1e30f;
  if (i < NT && j < NT) v = table[rel[i * NT + j] * NH + h];
  biasF[idx] = f2b(v);
}

// ---- fused window attention: 1 block = 1 window ----
__global__ __launch_bounds__(256, 2) void fused_winattn(
    const float* __restrict__ x, const float* __restrict__ projb,
    const unsigned short* __restrict__ wT, const unsigned short* __restrict__ projT,
    const float* __restrict__ qb, const unsigned short* __restrict__ biasF,
    float* __restrict__ out) {
  __shared__ Smem sm;
  const int tid  = threadIdx.x;
  const int lane = tid & 63;
  const int wave = tid >> 6;
  const int l15  = lane & 15;
  const int quad = lane >> 4;
  const int win  = blockIdx.x;

  // zero all LDS once: every padded/overflow fragment read stays finite
  {
    int4 z = {0, 0, 0, 0};
    int4* p = (int4*)&sm;
    for (int i = tid; i < (int)(sizeof(Smem) / 16); i += 256) p[i] = z;
  }
  __syncthreads();

  // stage 0: x -> bf16 LDS (coalesced float4, packed b64 LDS writes)
  const float* xw = x + (size_t)win * (NT * CDIM);
  for (int idx = tid; idx < NT * CDIM / 4; idx += 256) {
    int row = idx / 48, c4 = idx % 48;
    float4 v = ((const float4*)xw)[idx];
    ushort4 pk; pk.x = f2b(v.x); pk.y = f2b(v.y); pk.z = f2b(v.z); pk.w = f2b(v.w);
    *(ushort4*)&sm.xb[row][c4 * 4] = pk;
  }
  __syncthreads();

  for (int h = 0; h < NH; ++h) {
    // ---- G1: q,k computed swapped (A=wT,B=x => C[feat][tok], contiguous q/k stores),
    //          v computed normal  (A=x,B=wT => C[tok][feat], contiguous vT stores)
    for (int uu = 0; uu < 6; ++uu) {
      int u = wave * 6 + uu;                 // 24 units: 16 qk-swapped + 8 v-normal
      f32x4 acc = {0.f, 0.f, 0.f, 0.f};
      if (u < 16) {
        int mp = u >> 2, it = u & 3;         // feature tile (q:0,1  k:2,3), token tile
        int f0 = (mp < 2) ? (h * HD + mp * 16) : (CDIM + h * HD + (mp - 2) * 16);
        const unsigned short* wrow = wT + (size_t)(f0 + l15) * CDIM + quad * 8;
        const unsigned short* xrow = &sm.xb[0][0] + (size_t)(it * 16 + l15) * 200 + quad * 8;
        bf16x8 af[6], bf[6];
        #pragma unroll
        for (int k = 0; k < 6; ++k) af[k] = *(const bf16x8*)(wrow + k * 32);
        #pragma unroll
        for (int k = 0; k < 6; ++k) bf[k] = *(const bf16x8*)(xrow + k * 32);
        #pragma unroll
        for (int k = 0; k < 6; ++k)
          acc = __builtin_amdgcn_mfma_f32_16x16x32_bf16(af[k], bf[k], acc, 0, 0, 0);
        float4 bq = *(const float4*)(qb + f0 + quad * 4);  // bias per feature row
        acc[0] += bq.x; acc[1] += bq.y; acc[2] += bq.z; acc[3] += bq.w;
        int i = it * 16 + l15;               // token = C col
        if (i < NT) {
          int dl = (mp & 1) * 16 + quad * 4; // d-local 0..31
          unsigned short* dst = (mp < 2 ? &sm.qh[0][0] : &sm.kh[0][0]) + i * 40 + dl;
          ushort4 pk; pk.x = f2b(acc[0]); pk.y = f2b(acc[1]);
          pk.z = f2b(acc[2]); pk.w = f2b(acc[3]);
          *(ushort4*)dst = pk;
        }
      } else {
        int u2 = u - 16, dt = u2 >> 2, it = u2 & 3;
        int f0 = 2 * CDIM + h * HD + dt * 16;
        const unsigned short* xrow = &sm.xb[0][0] + (size_t)(it * 16 + l15) * 200 + quad * 8;
        const unsigned short* wrow = wT + (size_t)(f0 + l15) * CDIM + quad * 8;
        bf16x8 af[6], bf[6];
        #pragma unroll
        for (int k = 0; k < 6; ++k) af[k] = *(const bf16x8*)(xrow + k * 32);
        #pragma unroll
        for (int k = 0; k < 6; ++k) bf[k] = *(const bf16x8*)(wrow + k * 32);
        #pragma unroll
        for (int k = 0; k < 6; ++k)
          acc = __builtin_amdgcn_mfma_f32_16x16x32_bf16(af[k], bf[k], acc, 0, 0, 0);
        float bv = qb[f0 + l15];             // bias per feature col
        int d  = dt * 16 + l15;
        int j0 = it * 16 + quad * 4;
        // zero padded tokens j>=49 so P(0)*vT stays exactly 0 and finite
        ushort4 pk;
        pk.x = (j0 + 0 < NT) ? f2b(acc[0] + bv) : (unsigned short)0;
        pk.y = (j0 + 1 < NT) ? f2b(acc[1] + bv) : (unsigned short)0;
        pk.z = (j0 + 2 < NT) ? f2b(acc[2] + bv) : (unsigned short)0;
        pk.w = (j0 + 3 < NT) ? f2b(acc[3] + bv) : (unsigned short)0;
        *(ushort4*)&sm.vT[d][j0] = pk;
      }
    }
    __syncthreads();

    // ---- S = q·k^T (+bias, mask folded in), online row softmax; wave = i-tile
    {
      int it = wave;
      bf16x8 aq = *(const bf16x8*)(&sm.qh[0][0] + (size_t)(it * 16 + l15) * 40 + quad * 8);
      f32x4 s[4];
      #pragma unroll
      for (int jt = 0; jt < 4; ++jt) {
        bf16x8 bk = *(const bf16x8*)(&sm.kh[0][0] + (size_t)(jt * 16 + l15) * 40 + quad * 8);
        f32x4 z = {0.f, 0.f, 0.f, 0.f};
        s[jt] = __builtin_amdgcn_mfma_f32_16x16x32_bf16(aq, bk, z, 0, 0, 0);
        ushort4 bb = *(const ushort4*)(biasF + ((((h * 4 + it) * 4 + jt) * 64) + lane) * 4);
        s[jt][0] += b2f(bb.x); s[jt][1] += b2f(bb.y);
        s[jt][2] += b2f(bb.z); s[jt][3] += b2f(bb.w);
      }
      float pv[4][4];
      #pragma unroll
      for (int r = 0; r < 4; ++r) {          // row = quad*4+r; reduce across 16 lanes of quad
        float m = fmaxf(fmaxf(s[0][r], s[1][r]), fmaxf(s[2][r], s[3][r]));
        #pragma unroll
        for (int off = 1; off < 16; off <<= 1) m = fmaxf(m, __shfl_xor(m, off, 16));
        float sum = 0.f;
        #pragma unroll
        for (int jt = 0; jt < 4; ++jt) {
          float e = __expf(s[jt][r] - m);
          pv[jt][r] = e; sum += e;
        }
        #pragma unroll
        for (int off = 1; off < 16; off <<= 1) sum += __shfl_xor(sum, off, 16);
        if (l15 == 0) sm.sinv[it * 16 + quad * 4 + r] = 1.0f / sum;
      }
      #pragma unroll
      for (int jt = 0; jt < 4; ++jt)
        #pragma unroll
        for (int r = 0; r < 4; ++r)
          sm.P[it * 16 + quad * 4 + r][jt * 16 + l15] = f2b(pv[jt][r]);
    }
    __syncthreads();

    // ---- O = P·V (unnormalized), scale by 1/rowsum at store; wave = i-tile
    {
      int it = wave;
      bf16x8 ap[2];
      #pragma unroll
      for (int kk = 0; kk < 2; ++kk)
        ap[kk] = *(const bf16x8*)(&sm.P[0][0] + (size_t)(it * 16 + l15) * 72 + kk * 32 + quad * 8);
      #pragma unroll
      for (int dt = 0; dt < 2; ++dt) {
        f32x4 o = {0.f, 0.f, 0.f, 0.f};
        #pragma unroll
        for (int kk = 0; kk < 2; ++kk) {
          bf16x8 bv = *(const bf16x8*)(&sm.vT[0][0] + (size_t)(dt * 16 + l15) * 72 + kk * 32 + quad * 8);
          o = __builtin_amdgcn_mfma_f32_16x16x32_bf16(ap[kk], bv, o, 0, 0, 0);
        }
        int i0 = it * 16 + quad * 4;
        #pragma unroll
        for (int r = 0; r < 4; ++r) {
          int i = i0 + r;
          if (i < NT)
            sm.Ob[i][h * HD + dt * 16 + l15] = f2b(o[r] * sm.sinv[i]);
        }
      }
    }
    __syncthreads();   // protects q/k/vT/P reuse by next head, and Ob for proj
  }

  // ---- proj: out = Ob @ projT^T + b ; wave handles n-tiles {wave, wave+4, wave+8}
  for (int nn = 0; nn < 3; ++nn) {
    int nt = wave + nn * 4;
    int n0 = nt * 16;
    const unsigned short* wrow = projT + (size_t)(n0 + l15) * CDIM + quad * 8;
    bf16x8 bw[6];
    #pragma unroll
    for (int k = 0; k < 6; ++k) bw[k] = *(const bf16x8*)(wrow + k * 32);
    float pb = projb[n0 + l15];
    #pragma unroll
    for (int mt = 0; mt < 4; ++mt) {
      f32x4 acc = {0.f, 0.f, 0.f, 0.f};
      #pragma unroll
      for (int k = 0; k < 6; ++k) {
        bf16x8 ao = *(const bf16x8*)(&sm.Ob[0][0] + (size_t)(mt * 16 + l15) * 200 + k * 32 + quad * 8);
        acc = __builtin_amdgcn_mfma_f32_16x16x32_bf16(ao, bw[k], acc, 0, 0, 0);
      }
      int i0 = mt * 16 + quad * 4;
      #pragma unroll
      for (int r = 0; r < 4; ++r) {
        int i = i0 + r;
        if (i < NT)
          out[((size_t)win * NT + i) * CDIM + n0 + l15] = acc[r] + pb;
      }
    }
  }
}

extern "C" void kernel_launch(void* const* d_in, const int* in_sizes, int n_in,
                              void* d_out, int out_size, void* d_ws, size_t ws_size,
                              hipStream_t stream) {
  const float* x      = (const float*)d_in[0];
  const float* qkv_w  = (const float*)d_in[1];
  const float* qkv_b  = (const float*)d_in[2];
  const float* proj_w = (const float*)d_in[3];
  const float* proj_b = (const float*)d_in[4];
  const float* table  = (const float*)d_in[5];
  const int*   rel    = (const int*)d_in[6];
  float* out = (float*)d_out;

  char* ws = (char*)d_ws;                      // 346,368 B used
  unsigned short* wT    = (unsigned short*)(ws);                    // 576*192 bf16
  unsigned short* projT = (unsigned short*)(ws + 221184);           // 192*192 bf16
  float*          qb    = (float*)(ws + 221184 + 73728);            // 576 f32
  unsigned short* biasF = (unsigned short*)(ws + 221184 + 73728 + 2304); // 24576 bf16

  prep_w<<<579, 256, 0, stream>>>(qkv_w, qkv_b, proj_w, wT, projT, qb);
  prep_bias<<<96, 256, 0, stream>>>(table, rel, biasF);
  fused_winattn<<<NW, 256, 0, stream>>>(x, proj_b, wT, projT, qb, biasF, out);
}